// Round 1
// baseline (93.839 us; speedup 1.0000x reference)
//
#include <hip/hip_runtime.h>
#include <math.h>

// Problem constants (from setup_inputs: B=2, N=512, E=128, H=8, D=16)
#define BATCH 2
#define NSEQ  512
#define EDIM  128
#define HNUM  8
#define DDIM  16
#define MROWS (BATCH*NSEQ)   // 1024

// ---------------------------------------------------------------------------
// Generic small GEMM: C[M,N] = A[M,K=128] * B[N,K=128]^T (+ optional bias)
// BM x BN tile fully staged in LDS (K=128 fits), 256 threads,
// micro-tile TM x TN with (BM/TM)*(BN/TN) == 256.
// ---------------------------------------------------------------------------
template<int BM, int BN, int TM, int TN>
__global__ __launch_bounds__(256)
void gemm_tn(const float* __restrict__ A, const float* __restrict__ B,
             const float* __restrict__ bias, float* __restrict__ C,
             int M, int N) {
    constexpr int K  = 128;
    constexpr int KP = K + 1;                 // +1 pad: breaks pow2 bank strides
    __shared__ float As[BM][KP];
    __shared__ float Bs[BN][KP];

    const int tid  = threadIdx.x;
    const int row0 = blockIdx.y * BM;
    const int col0 = blockIdx.x * BN;

    // Stage A tile (BM x 128) via coalesced float4 loads
    #pragma unroll
    for (int it = 0; it < (BM * 32) / 256; ++it) {
        int idx = tid + it * 256;
        int r = idx >> 5, c4 = idx & 31;
        float4 v = *(const float4*)(A + (size_t)(row0 + r) * K + c4 * 4);
        As[r][c4*4+0] = v.x; As[r][c4*4+1] = v.y;
        As[r][c4*4+2] = v.z; As[r][c4*4+3] = v.w;
    }
    // Stage B tile (BN x 128)
    #pragma unroll
    for (int it = 0; it < (BN * 32) / 256; ++it) {
        int idx = tid + it * 256;
        int r = idx >> 5, c4 = idx & 31;
        float4 v = *(const float4*)(B + (size_t)(col0 + r) * K + c4 * 4);
        Bs[r][c4*4+0] = v.x; Bs[r][c4*4+1] = v.y;
        Bs[r][c4*4+2] = v.z; Bs[r][c4*4+3] = v.w;
    }
    __syncthreads();

    const int tx = tid & 15;   // 16 col-groups
    const int ty = tid >> 4;   // 16 row-groups
    float acc[TM][TN] = {};

    for (int kk = 0; kk < K; ++kk) {
        float a[TM], b[TN];
        #pragma unroll
        for (int i = 0; i < TM; ++i) a[i] = As[ty*TM + i][kk];
        #pragma unroll
        for (int j = 0; j < TN; ++j) b[j] = Bs[tx*TN + j][kk];
        #pragma unroll
        for (int i = 0; i < TM; ++i)
            #pragma unroll
            for (int j = 0; j < TN; ++j)
                acc[i][j] = fmaf(a[i], b[j], acc[i][j]);
    }

    #pragma unroll
    for (int i = 0; i < TM; ++i) {
        int r = row0 + ty*TM + i;
        #pragma unroll
        for (int j = 0; j < TN; ++j) {
            int cc = col0 + tx*TN + j;
            float v = acc[i][j];
            if (bias) v += bias[cc];
            C[(size_t)r * N + cc] = v;
        }
    }
}

// ---------------------------------------------------------------------------
// Edge-weighted attention core. One wave (64 lanes) per (b,h,n).
// lane = m within chunks of 64; dots & e-row live in registers (8 chunks).
//   dots[m] = (q.k + sum_d q_d * lrelu(e_nm*wk_d + bk_d)) * 0.25 * log2(e)
//   p = exp2(dots - max); hat_d = v_d + (sum_m p * lrelu(e_nm*wv_d+bv_d))/sum_p
// (sum_m attn == 1 exactly in softmax, so v term factors out.)
// ---------------------------------------------------------------------------
__global__ __launch_bounds__(256)
void attn_kernel(const float* __restrict__ qkv, const float* __restrict__ e,
                 const float* __restrict__ wekv, const float* __restrict__ bekv,
                 float* __restrict__ hat) {
    const int lane = threadIdx.x & 63;
    const int wv   = threadIdx.x >> 6;            // wave id in block (0..3)
    const int idx  = blockIdx.x * 4 + wv;         // (b*N + n)*H + h, 0..8191
    const int h    = idx & (HNUM - 1);
    const int bn   = idx >> 3;                    // b*N + n

    const float* qrow = qkv + (size_t)bn * (3 * EDIM) + h * DDIM;  // [B,N,3,H,D]
    const float* krow = qrow + EDIM;
    const float* vrow = qrow + 2 * EDIM;
    const float* erow = e + (size_t)bn * NSEQ;

    // Per-wave constants: q fragment, K-branch edge weights, q.k
    float q[DDIM], wk[DDIM], bk[DDIM];
    float qk = 0.f;
    #pragma unroll
    for (int d = 0; d < DDIM; ++d) {
        q[d]  = qrow[d];
        qk    = fmaf(q[d], krow[d], qk);
        wk[d] = wekv[h * DDIM + d];
        bk[d] = bekv[h * DDIM + d];
    }

    const float SC = 0.25f * 1.44269504088896340736f;  // 1/sqrt(D) * log2(e)

    // Pass 1: dots (scaled to log2 domain) + running max
    float dots[NSEQ / 64], ev[NSEQ / 64];
    float lmax = -1e30f;
    #pragma unroll
    for (int c = 0; c < NSEQ / 64; ++c) {
        float s = erow[c * 64 + lane];             // coalesced
        ev[c] = s;
        float dot = qk;
        #pragma unroll
        for (int d = 0; d < DDIM; ++d) {
            float t = fmaf(s, wk[d], bk[d]);
            t = fmaxf(t, 0.01f * t);               // LeakyReLU(0.01)
            dot = fmaf(q[d], t, dot);
        }
        dot *= SC;
        dots[c] = dot;
        lmax = fmaxf(lmax, dot);
    }
    #pragma unroll
    for (int off = 32; off >= 1; off >>= 1)
        lmax = fmaxf(lmax, __shfl_xor(lmax, off, 64));

    // Pass 2: p = exp2(dot - max); accumulate sum_p and sum_m p*lrelu(e*wv+bv)
    float wvv[DDIM], bv[DDIM], acc[DDIM];
    #pragma unroll
    for (int d = 0; d < DDIM; ++d) {
        wvv[d] = wekv[EDIM + h * DDIM + d];
        bv[d]  = bekv[EDIM + h * DDIM + d];
        acc[d] = 0.f;
    }
    float sp = 0.f;
    #pragma unroll
    for (int c = 0; c < NSEQ / 64; ++c) {
        float p = __builtin_exp2f(dots[c] - lmax);
        sp += p;
        float s = ev[c];
        #pragma unroll
        for (int d = 0; d < DDIM; ++d) {
            float t = fmaf(s, wvv[d], bv[d]);
            t = fmaxf(t, 0.01f * t);
            acc[d] = fmaf(p, t, acc[d]);
        }
    }

    // Butterfly reduce: after this every lane holds the full sums
    #pragma unroll
    for (int off = 1; off < 64; off <<= 1) {
        sp += __shfl_xor(sp, off, 64);
        #pragma unroll
        for (int d = 0; d < DDIM; ++d)
            acc[d] += __shfl_xor(acc[d], off, 64);
    }

    // Lane d (d<16) selects acc[d] via cndmask chain, writes hat[b,n,h*16+d]
    float a = acc[0];
    #pragma unroll
    for (int d = 1; d < DDIM; ++d) a = (lane == d) ? acc[d] : a;
    if (lane < DDIM) {
        float o = vrow[lane] + a / sp;
        hat[(size_t)bn * EDIM + h * DDIM + lane] = o;
    }
}

// ---------------------------------------------------------------------------
extern "C" void kernel_launch(void* const* d_in, const int* in_sizes, int n_in,
                              void* d_out, int out_size, void* d_ws, size_t ws_size,
                              hipStream_t stream) {
    const float* x     = (const float*)d_in[0];  // [B,N,128]
    const float* e     = (const float*)d_in[1];  // [B,N,N]
    const float* w_qkv = (const float*)d_in[2];  // [384,128]
    const float* w_ekv = (const float*)d_in[3];  // [256,1] -> flat 256
    const float* b_ekv = (const float*)d_in[4];  // [256]
    const float* w_prj = (const float*)d_in[5];  // [128,128]
    const float* b_prj = (const float*)d_in[6];  // [128]
    float* out = (float*)d_out;

    float* qkv = (float*)d_ws;                   // [1024, 384]
    float* hat = qkv + (size_t)MROWS * 3 * EDIM; // [1024, 128]

    // 1) QKV projection: [1024,384] = x[1024,128] @ w_qkv[384,128]^T
    gemm_tn<32, 64, 2, 4><<<dim3(384 / 64, MROWS / 32), 256, 0, stream>>>(
        x, w_qkv, nullptr, qkv, MROWS, 3 * EDIM);

    // 2) Edge-weighted attention -> hat [1024,128]
    attn_kernel<<<(BATCH * NSEQ * HNUM) / 4, 256, 0, stream>>>(
        qkv, e, w_ekv, b_ekv, hat);

    // 3) Output projection: out[1024,128] = hat @ w_prj[128,128]^T + b_prj
    gemm_tn<32, 32, 2, 2><<<dim3(128 / 32, MROWS / 32), 256, 0, stream>>>(
        hat, w_prj, b_prj, out, MROWS, EDIM);
}